// Round 1
// baseline (1551.313 us; speedup 1.0000x reference)
//
#include <hip/hip_runtime.h>
#include <math.h>

#define SB 8192
#define NB 32
#define WC 64
#define NM 16
#define NKC 32   // 2*NM (cos,sin interleaved)
#define NP 24

// ws layout (float offsets):
//   h    : 0         (B*W*S = 16777216)
//   T    : 16777216  (S*32  = 262144)
//   xf   : 17039360  (B*W*32 = 65536)
//   of   : 17104896  (B*W*32 = 65536)
//   icaT : 17170432  (128*24 = 3072)

// Build DFT table: T[s][2k] = cos(2*pi*k*s/S), T[s][2k+1] = sin(2*pi*k*s/S)
__global__ __launch_bounds__(256) void k_table(float* __restrict__ T) {
    int s = blockIdx.x * 256 + threadIdx.x;   // exactly 8192 threads
    float* row = T + (size_t)s * NKC;
    #pragma unroll
    for (int k = 0; k < NM; ++k) {
        int m = (k * s) & (SB - 1);           // exact phase mod S
        double ang = (double)m * (6.283185307179586476925286766559 / (double)SB);
        row[2 * k]     = (float)cos(ang);
        row[2 * k + 1] = (float)sin(ang);
    }
}

// icaT[c][p] = fc2_w[0][c] * ica_w[p][c]  (fold fc2 into ica, transpose for contiguous reads)
__global__ __launch_bounds__(256) void k_prep(const float* __restrict__ ica_w,
                                              const float* __restrict__ fc2_w,
                                              float* __restrict__ icaT) {
    int tid = blockIdx.x * 256 + threadIdx.x;   // exactly 3072
    int c = tid / NP;
    int p = tid - c * NP;
    icaT[c * NP + p] = ica_w[p * 128 + c] * fc2_w[c];
}

// lift: h[b][w][s] = x[b][s][0]*fc0_w[w][0] + x[b][s][1]*fc0_w[w][1] + fc0_b[w]
__global__ __launch_bounds__(256) void k_lift(const float* __restrict__ x,
                                              const float* __restrict__ fc0_w,
                                              const float* __restrict__ fc0_b,
                                              float* __restrict__ h) {
    int b = blockIdx.y;
    int s = blockIdx.x * 256 + threadIdx.x;
    float2 xv = ((const float2*)x)[(size_t)b * SB + s];
    #pragma unroll
    for (int w = 0; w < WC; ++w) {
        float v = fmaf(xv.x, fc0_w[2 * w], fmaf(xv.y, fc0_w[2 * w + 1], fc0_b[w]));
        h[((size_t)(b * WC + w)) * SB + s] = v;
    }
}

// forward DFT (first 16 modes): xf[b][i][2k]=sum_s h*cos, [2k+1]=sum_s h*sin
// block = (b, group of 4 channels), full-S reduction, 256 threads
__global__ __launch_bounds__(256, 2) void k_dft(const float* __restrict__ h,
                                                const float* __restrict__ T,
                                                float* __restrict__ xf) {
    int blk = blockIdx.x;           // b*16 + ig
    int b  = blk >> 4;
    int i0 = (blk & 15) * 4;
    int t  = threadIdx.x;

    float acc[4][NKC];
    #pragma unroll
    for (int ii = 0; ii < 4; ++ii)
        #pragma unroll
        for (int j = 0; j < NKC; ++j) acc[ii][j] = 0.f;

    const float* hbase = h + ((size_t)(b * WC + i0)) * SB;
    for (int sit = 0; sit < 32; ++sit) {
        int s = sit * 256 + t;
        float tv[NKC];
        const float4* Trow = (const float4*)(T + (size_t)s * NKC);
        #pragma unroll
        for (int q = 0; q < 8; ++q) {
            float4 v = Trow[q];
            tv[4*q] = v.x; tv[4*q+1] = v.y; tv[4*q+2] = v.z; tv[4*q+3] = v.w;
        }
        #pragma unroll
        for (int ii = 0; ii < 4; ++ii) {
            float hv = hbase[(size_t)ii * SB + s];
            #pragma unroll
            for (int j = 0; j < NKC; ++j)
                acc[ii][j] = fmaf(hv, tv[j], acc[ii][j]);
        }
    }

    // full 64-lane xor butterfly (all lanes end with wave sum)
    #pragma unroll
    for (int ii = 0; ii < 4; ++ii)
        #pragma unroll
        for (int j = 0; j < NKC; ++j) {
            float v = acc[ii][j];
            #pragma unroll
            for (int m = 1; m < 64; m <<= 1) v += __shfl_xor(v, m);
            acc[ii][j] = v;
        }

    __shared__ float red[4][128];
    int wave = t >> 6;
    int lane = t & 63;
    if (lane == 0) {   // static-indexed writes only (keep acc in registers)
        #pragma unroll
        for (int ii = 0; ii < 4; ++ii)
            #pragma unroll
            for (int j = 0; j < NKC; ++j)
                red[wave][ii * NKC + j] = acc[ii][j];
    }
    __syncthreads();
    if (t < 128) {
        float r = red[0][t] + red[1][t] + red[2][t] + red[3][t];
        int ii = t >> 5, j = t & 31;
        xf[((size_t)(b * WC + i0 + ii)) * NKC + j] = r;
    }
}

// mode mix: of[b][o][2k] = alpha*Re, of[b][o][2k+1] = -alpha*Im   (sign folded so
// inverse is a plain dot product with T row). xf stores (sum cos, sum sin); true
// xfr = cs.x, xfi = -cs.y.
__global__ __launch_bounds__(256) void k_mix(const float* __restrict__ xf,
                                             const float* __restrict__ wr,
                                             const float* __restrict__ wi,
                                             float* __restrict__ of) {
    int tid = blockIdx.x * 256 + threadIdx.x;   // exactly 32768
    int k = tid & 15;
    int o = (tid >> 4) & 63;
    int b = tid >> 10;
    float orr = 0.f, oii = 0.f;
    const float2* xfb = (const float2*)(xf + (size_t)b * WC * NKC);
    #pragma unroll 4
    for (int i = 0; i < WC; ++i) {
        float2 cs = xfb[i * NM + k];
        float wrv = wr[(i * WC + o) * NM + k];
        float wiv = wi[(i * WC + o) * NM + k];
        orr = fmaf(cs.x, wrv, fmaf(cs.y, wiv, orr));    // xfr*wr - xfi*wi
        oii = fmaf(cs.x, wiv, fmaf(-cs.y, wrv, oii));   // xfr*wi + xfi*wr
    }
    float alpha = (k == 0 ? 1.f : 2.f) / (float)SB;
    float2 res = make_float2(alpha * orr, -alpha * oii);
    ((float2*)of)[(size_t)(b * WC + o) * NM + k] = res;
}

// fused inverse-DFT + pointwise conv + bias + relu, in-place on h.
// thread owns one s-column: reads h[b][:][s], writes h[b][:][s] (thread-local).
__global__ __launch_bounds__(256, 3) void k_update(float* __restrict__ h,
                                                   const float* __restrict__ T,
                                                   const float* __restrict__ of,
                                                   const float* __restrict__ pw,
                                                   const float* __restrict__ pwb,
                                                   int relu) {
    int b = blockIdx.y;
    int s = blockIdx.x * 256 + threadIdx.x;

    float tv[NKC];
    const float4* Trow = (const float4*)(T + (size_t)s * NKC);
    #pragma unroll
    for (int q = 0; q < 8; ++q) {
        float4 v = Trow[q];
        tv[4*q] = v.x; tv[4*q+1] = v.y; tv[4*q+2] = v.z; tv[4*q+3] = v.w;
    }

    float hv[WC];
    float* hcol = h + (size_t)b * WC * SB + s;
    #pragma unroll
    for (int i = 0; i < WC; ++i) hv[i] = hcol[(size_t)i * SB];

    const float* ofb = of + (size_t)b * WC * NKC;
    for (int o = 0; o < WC; ++o) {
        float acc = pwb[o];
        const float* ofp = ofb + o * NKC;
        #pragma unroll
        for (int j = 0; j < NKC; ++j) acc = fmaf(ofp[j], tv[j], acc);
        const float* pwo = pw + o * WC;
        #pragma unroll
        for (int i = 0; i < WC; ++i) acc = fmaf(pwo[i], hv[i], acc);
        if (relu) acc = fmaxf(acc, 0.f);
        hcol[(size_t)o * SB] = acc;
    }
}

// final: per (b,s): t = relu(fc1_w @ h[:,s] + fc1_b); tc[p] = sum_c t[c]*icaT[c][p] + ica_b[p];
// out = sum_p tc[p]
__global__ __launch_bounds__(256, 3) void k_final(const float* __restrict__ h,
                                                  const float* __restrict__ fc1_w,
                                                  const float* __restrict__ fc1_b,
                                                  const float* __restrict__ icaT,
                                                  const float* __restrict__ ica_b,
                                                  float* __restrict__ out,
                                                  float* __restrict__ tc) {
    int b = blockIdx.y;
    int s = blockIdx.x * 256 + threadIdx.x;

    float hv[WC];
    const float* hcol = h + (size_t)b * WC * SB + s;
    #pragma unroll
    for (int i = 0; i < WC; ++i) hv[i] = hcol[(size_t)i * SB];

    float acc[NP];
    #pragma unroll
    for (int p = 0; p < NP; ++p) acc[p] = ica_b[p];

    for (int c = 0; c < 128; ++c) {
        float tval = fc1_b[c];
        const float* w = fc1_w + c * WC;
        #pragma unroll
        for (int i = 0; i < WC; ++i) tval = fmaf(w[i], hv[i], tval);
        tval = fmaxf(tval, 0.f);
        const float* e = icaT + c * NP;
        #pragma unroll
        for (int p = 0; p < NP; ++p) acc[p] = fmaf(tval, e[p], acc[p]);
    }

    float osum = 0.f;
    #pragma unroll
    for (int p = 0; p < NP; ++p) osum += acc[p];
    size_t idx = (size_t)b * SB + s;
    out[idx] = osum;

    float4* t4 = (float4*)(tc + idx * NP);   // 96B stride => 16B aligned
    t4[0] = make_float4(acc[0],  acc[1],  acc[2],  acc[3]);
    t4[1] = make_float4(acc[4],  acc[5],  acc[6],  acc[7]);
    t4[2] = make_float4(acc[8],  acc[9],  acc[10], acc[11]);
    t4[3] = make_float4(acc[12], acc[13], acc[14], acc[15]);
    t4[4] = make_float4(acc[16], acc[17], acc[18], acc[19]);
    t4[5] = make_float4(acc[20], acc[21], acc[22], acc[23]);
}

extern "C" void kernel_launch(void* const* d_in, const int* in_sizes, int n_in,
                              void* d_out, int out_size, void* d_ws, size_t ws_size,
                              hipStream_t stream) {
    const float* x     = (const float*)d_in[0];
    const float* fc0_w = (const float*)d_in[1];
    const float* fc0_b = (const float*)d_in[2];
    const float* cwr   = (const float*)d_in[3];
    const float* cwi   = (const float*)d_in[4];
    const float* pw_w  = (const float*)d_in[5];
    const float* pw_b  = (const float*)d_in[6];
    const float* fc1_w = (const float*)d_in[7];
    const float* fc1_b = (const float*)d_in[8];
    const float* fc2_w = (const float*)d_in[9];
    const float* ica_w = (const float*)d_in[10];
    const float* ica_b = (const float*)d_in[11];

    float* out = (float*)d_out;            // (B,S,1) = 262144
    float* tc  = out + (size_t)NB * SB;    // (B,S,1,24) = 6291456

    float* ws   = (float*)d_ws;
    float* h    = ws;
    float* T    = ws + 16777216;
    float* xf   = ws + 17039360;
    float* of   = ws + 17104896;
    float* icaT = ws + 17170432;

    k_table<<<32, 256, 0, stream>>>(T);
    k_prep<<<12, 256, 0, stream>>>(ica_w, fc2_w, icaT);
    k_lift<<<dim3(32, 32), 256, 0, stream>>>(x, fc0_w, fc0_b, h);

    for (int l = 0; l < 4; ++l) {
        k_dft<<<512, 256, 0, stream>>>(h, T, xf);
        k_mix<<<128, 256, 0, stream>>>(xf, cwr + (size_t)l * WC * WC * NM,
                                       cwi + (size_t)l * WC * WC * NM, of);
        k_update<<<dim3(32, 32), 256, 0, stream>>>(h, T, of,
                                                   pw_w + (size_t)l * WC * WC,
                                                   pw_b + (size_t)l * WC,
                                                   (l < 3) ? 1 : 0);
    }

    k_final<<<dim3(32, 32), 256, 0, stream>>>(h, fc1_w, fc1_b, icaT, ica_b, out, tc);
}

// Round 2
// 915.944 us; speedup vs baseline: 1.6937x; 1.6937x over previous
//
#include <hip/hip_runtime.h>
#include <math.h>

#define SB 8192
#define NB 32
#define WC 64
#define NM 16
#define NKC 32   // 2*NM (cos,sin interleaved)
#define NP 24

// ws layout (float offsets):
//   h    : 0         (B*W*S = 16777216)
//   T    : 16777216  (S*32  = 262144)
//   xf   : 17039360  (B*W*32 = 65536)
//   of   : 17104896  (B*W*32 = 65536)
//   icaT : 17170432  (128*24 = 3072)

// Build DFT table: T[s][2k] = cos(2*pi*k*s/S), T[s][2k+1] = sin(2*pi*k*s/S)
__global__ __launch_bounds__(256) void k_table(float* __restrict__ T) {
    int s = blockIdx.x * 256 + threadIdx.x;   // exactly 8192 threads
    float* row = T + (size_t)s * NKC;
    #pragma unroll
    for (int k = 0; k < NM; ++k) {
        int m = (k * s) & (SB - 1);           // exact phase mod S
        double ang = (double)m * (6.283185307179586476925286766559 / (double)SB);
        row[2 * k]     = (float)cos(ang);
        row[2 * k + 1] = (float)sin(ang);
    }
}

// icaT[c][p] = fc2_w[0][c] * ica_w[p][c]  (fold fc2 into ica, transpose for contiguous reads)
__global__ __launch_bounds__(256) void k_prep(const float* __restrict__ ica_w,
                                              const float* __restrict__ fc2_w,
                                              float* __restrict__ icaT) {
    int tid = blockIdx.x * 256 + threadIdx.x;   // exactly 3072
    int c = tid / NP;
    int p = tid - c * NP;
    icaT[c * NP + p] = ica_w[p * 128 + c] * fc2_w[c];
}

// lift: h[b][w][s] = x[b][s][0]*fc0_w[w][0] + x[b][s][1]*fc0_w[w][1] + fc0_b[w]
__global__ __launch_bounds__(256) void k_lift(const float* __restrict__ x,
                                              const float* __restrict__ fc0_w,
                                              const float* __restrict__ fc0_b,
                                              float* __restrict__ h) {
    int b = blockIdx.y;
    int s = blockIdx.x * 256 + threadIdx.x;
    float2 xv = ((const float2*)x)[(size_t)b * SB + s];
    #pragma unroll
    for (int w = 0; w < WC; ++w) {
        float v = fmaf(xv.x, fc0_w[2 * w], fmaf(xv.y, fc0_w[2 * w + 1], fc0_b[w]));
        h[((size_t)(b * WC + w)) * SB + s] = v;
    }
}

// forward DFT (first 16 modes): xf[b][i][2k]=sum_s h*cos, [2k+1]=sum_s h*sin
// block = (b, group of 4 channels), full-S reduction, 256 threads
__global__ __launch_bounds__(256, 2) void k_dft(const float* __restrict__ h,
                                                const float* __restrict__ T,
                                                float* __restrict__ xf) {
    int blk = blockIdx.x;           // b*16 + ig
    int b  = blk >> 4;
    int i0 = (blk & 15) * 4;
    int t  = threadIdx.x;

    float acc[4][NKC];
    #pragma unroll
    for (int ii = 0; ii < 4; ++ii)
        #pragma unroll
        for (int j = 0; j < NKC; ++j) acc[ii][j] = 0.f;

    const float* hbase = h + ((size_t)(b * WC + i0)) * SB;
    for (int sit = 0; sit < 32; ++sit) {
        int s = sit * 256 + t;
        float tv[NKC];
        const float4* Trow = (const float4*)(T + (size_t)s * NKC);
        #pragma unroll
        for (int q = 0; q < 8; ++q) {
            float4 v = Trow[q];
            tv[4*q] = v.x; tv[4*q+1] = v.y; tv[4*q+2] = v.z; tv[4*q+3] = v.w;
        }
        #pragma unroll
        for (int ii = 0; ii < 4; ++ii) {
            float hv = hbase[(size_t)ii * SB + s];
            #pragma unroll
            for (int j = 0; j < NKC; ++j)
                acc[ii][j] = fmaf(hv, tv[j], acc[ii][j]);
        }
    }

    // full 64-lane xor butterfly (all lanes end with wave sum)
    #pragma unroll
    for (int ii = 0; ii < 4; ++ii)
        #pragma unroll
        for (int j = 0; j < NKC; ++j) {
            float v = acc[ii][j];
            #pragma unroll
            for (int m = 1; m < 64; m <<= 1) v += __shfl_xor(v, m);
            acc[ii][j] = v;
        }

    __shared__ float red[4][128];
    int wave = t >> 6;
    int lane = t & 63;
    if (lane == 0) {   // static-indexed writes only (keep acc in registers)
        #pragma unroll
        for (int ii = 0; ii < 4; ++ii)
            #pragma unroll
            for (int j = 0; j < NKC; ++j)
                red[wave][ii * NKC + j] = acc[ii][j];
    }
    __syncthreads();
    if (t < 128) {
        float r = red[0][t] + red[1][t] + red[2][t] + red[3][t];
        int ii = t >> 5, j = t & 31;
        xf[((size_t)(b * WC + i0 + ii)) * NKC + j] = r;
    }
}

// mode mix: of[b][o][2k] = alpha*Re, of[b][o][2k+1] = -alpha*Im
__global__ __launch_bounds__(256) void k_mix(const float* __restrict__ xf,
                                             const float* __restrict__ wr,
                                             const float* __restrict__ wi,
                                             float* __restrict__ of) {
    int tid = blockIdx.x * 256 + threadIdx.x;   // exactly 32768
    int k = tid & 15;
    int o = (tid >> 4) & 63;
    int b = tid >> 10;
    float orr = 0.f, oii = 0.f;
    const float2* xfb = (const float2*)(xf + (size_t)b * WC * NKC);
    #pragma unroll 4
    for (int i = 0; i < WC; ++i) {
        float2 cs = xfb[i * NM + k];
        float wrv = wr[(i * WC + o) * NM + k];
        float wiv = wi[(i * WC + o) * NM + k];
        orr = fmaf(cs.x, wrv, fmaf(cs.y, wiv, orr));    // xfr*wr - xfi*wi
        oii = fmaf(cs.x, wiv, fmaf(-cs.y, wrv, oii));   // xfr*wi + xfi*wr
    }
    float alpha = (k == 0 ? 1.f : 2.f) / (float)SB;
    float2 res = make_float2(alpha * orr, -alpha * oii);
    ((float2*)of)[(size_t)(b * WC + o) * NM + k] = res;
}

// fused inverse-DFT + pointwise conv + bias + relu, in-place on h.
// GEMM form: acc[o] = bias[o] + sum_{k<64} pw[o][k]*h[k][s] + sum_{j<32} of[o][j]*T[s][j]
// Weight block At[96][64] staged in LDS (transposed), read via broadcast ds_read_b128.
__global__ __launch_bounds__(256, 3) void k_update(float* __restrict__ h,
                                                   const float* __restrict__ T,
                                                   const float* __restrict__ of,
                                                   const float* __restrict__ pw,
                                                   const float* __restrict__ pwb,
                                                   int relu) {
    __shared__ float At[96][64];   // 24 KB; At[k][o]
    int b = blockIdx.y;
    int s = blockIdx.x * 256 + threadIdx.x;

    const float* ofb = of + (size_t)b * WC * NKC;
    for (int e = threadIdx.x; e < 96 * 64; e += 256) {
        int k = e >> 6, o = e & 63;
        At[k][o] = (k < 64) ? pw[o * 64 + k] : ofb[o * 32 + (k - 64)];
    }

    float* hcol = h + (size_t)b * WC * SB + s;
    float acc[64];
    #pragma unroll
    for (int o = 0; o < 64; ++o) acc[o] = pwb[o];
    __syncthreads();

    // pointwise part: K = 64, chunks of 8
    for (int kc = 0; kc < 8; ++kc) {
        float xs[8];
        #pragma unroll
        for (int u = 0; u < 8; ++u) xs[u] = hcol[(size_t)(kc * 8 + u) * SB];
        #pragma unroll
        for (int u = 0; u < 8; ++u) {
            const float4* arow = (const float4*)At[kc * 8 + u];
            #pragma unroll
            for (int o4 = 0; o4 < 16; ++o4) {
                float4 a = arow[o4];
                acc[o4*4+0] = fmaf(a.x, xs[u], acc[o4*4+0]);
                acc[o4*4+1] = fmaf(a.y, xs[u], acc[o4*4+1]);
                acc[o4*4+2] = fmaf(a.z, xs[u], acc[o4*4+2]);
                acc[o4*4+3] = fmaf(a.w, xs[u], acc[o4*4+3]);
            }
        }
    }
    // inverse-DFT part: K = 32, chunks of 8
    const float4* Trow = (const float4*)(T + (size_t)s * NKC);
    for (int kc = 0; kc < 4; ++kc) {
        float4 v0 = Trow[kc * 2], v1 = Trow[kc * 2 + 1];
        float xs[8] = {v0.x, v0.y, v0.z, v0.w, v1.x, v1.y, v1.z, v1.w};
        #pragma unroll
        for (int u = 0; u < 8; ++u) {
            const float4* arow = (const float4*)At[64 + kc * 8 + u];
            #pragma unroll
            for (int o4 = 0; o4 < 16; ++o4) {
                float4 a = arow[o4];
                acc[o4*4+0] = fmaf(a.x, xs[u], acc[o4*4+0]);
                acc[o4*4+1] = fmaf(a.y, xs[u], acc[o4*4+1]);
                acc[o4*4+2] = fmaf(a.z, xs[u], acc[o4*4+2]);
                acc[o4*4+3] = fmaf(a.w, xs[u], acc[o4*4+3]);
            }
        }
    }

    #pragma unroll
    for (int o = 0; o < 64; ++o) {
        float v = acc[o];
        if (relu) v = fmaxf(v, 0.f);
        hcol[(size_t)o * SB] = v;
    }
}

// final: t = relu(fc1_w @ h[:,s] + fc1_b); tc[p] = sum_c t[c]*icaT[c][p] + ica_b[p]; out = sum_p tc
// fc1_w (32 KB) + icaT (12 KB) staged in LDS, broadcast reads; hv[64]/acc[24] in registers.
__global__ __launch_bounds__(256, 3) void k_final(const float* __restrict__ h,
                                                  const float* __restrict__ fc1_w,
                                                  const float* __restrict__ fc1_b,
                                                  const float* __restrict__ icaT,
                                                  const float* __restrict__ ica_b,
                                                  float* __restrict__ out,
                                                  float* __restrict__ tc) {
    __shared__ float w1[128][64];   // 32 KB
    __shared__ float e1[128][24];   // 12 KB (row stride 96B, float4-aligned)
    __shared__ float b1[128];
    int b = blockIdx.y;
    int s = blockIdx.x * 256 + threadIdx.x;

    for (int e = threadIdx.x; e < 128 * 64; e += 256) ((float*)w1)[e] = fc1_w[e];
    for (int e = threadIdx.x; e < 128 * NP; e += 256) ((float*)e1)[e] = icaT[e];
    if (threadIdx.x < 128) b1[threadIdx.x] = fc1_b[threadIdx.x];

    float hv[64];
    const float* hcol = h + (size_t)b * WC * SB + s;
    #pragma unroll
    for (int i = 0; i < 64; ++i) hv[i] = hcol[(size_t)i * SB];

    float acc[NP];
    #pragma unroll
    for (int p = 0; p < NP; ++p) acc[p] = ica_b[p];
    __syncthreads();

    for (int cc = 0; cc < 16; ++cc) {
        float tv8[8];
        #pragma unroll
        for (int u = 0; u < 8; ++u) {
            int c = cc * 8 + u;
            float t = b1[c];
            const float4* wrow = (const float4*)w1[c];
            #pragma unroll
            for (int i4 = 0; i4 < 16; ++i4) {
                float4 wv = wrow[i4];
                t = fmaf(wv.x, hv[i4*4+0],
                    fmaf(wv.y, hv[i4*4+1],
                    fmaf(wv.z, hv[i4*4+2],
                    fmaf(wv.w, hv[i4*4+3], t))));
            }
            tv8[u] = fmaxf(t, 0.f);
        }
        #pragma unroll
        for (int u = 0; u < 8; ++u) {
            const float4* erow = (const float4*)e1[cc * 8 + u];
            #pragma unroll
            for (int p4 = 0; p4 < 6; ++p4) {
                float4 ev = erow[p4];
                acc[p4*4+0] = fmaf(tv8[u], ev.x, acc[p4*4+0]);
                acc[p4*4+1] = fmaf(tv8[u], ev.y, acc[p4*4+1]);
                acc[p4*4+2] = fmaf(tv8[u], ev.z, acc[p4*4+2]);
                acc[p4*4+3] = fmaf(tv8[u], ev.w, acc[p4*4+3]);
            }
        }
    }

    float osum = 0.f;
    #pragma unroll
    for (int p = 0; p < NP; ++p) osum += acc[p];
    size_t idx = (size_t)b * SB + s;
    out[idx] = osum;

    float4* t4 = (float4*)(tc + idx * NP);   // 96B stride => 16B aligned
    t4[0] = make_float4(acc[0],  acc[1],  acc[2],  acc[3]);
    t4[1] = make_float4(acc[4],  acc[5],  acc[6],  acc[7]);
    t4[2] = make_float4(acc[8],  acc[9],  acc[10], acc[11]);
    t4[3] = make_float4(acc[12], acc[13], acc[14], acc[15]);
    t4[4] = make_float4(acc[16], acc[17], acc[18], acc[19]);
    t4[5] = make_float4(acc[20], acc[21], acc[22], acc[23]);
}

extern "C" void kernel_launch(void* const* d_in, const int* in_sizes, int n_in,
                              void* d_out, int out_size, void* d_ws, size_t ws_size,
                              hipStream_t stream) {
    const float* x     = (const float*)d_in[0];
    const float* fc0_w = (const float*)d_in[1];
    const float* fc0_b = (const float*)d_in[2];
    const float* cwr   = (const float*)d_in[3];
    const float* cwi   = (const float*)d_in[4];
    const float* pw_w  = (const float*)d_in[5];
    const float* pw_b  = (const float*)d_in[6];
    const float* fc1_w = (const float*)d_in[7];
    const float* fc1_b = (const float*)d_in[8];
    const float* fc2_w = (const float*)d_in[9];
    const float* ica_w = (const float*)d_in[10];
    const float* ica_b = (const float*)d_in[11];

    float* out = (float*)d_out;            // (B,S,1) = 262144
    float* tc  = out + (size_t)NB * SB;    // (B,S,1,24) = 6291456

    float* ws   = (float*)d_ws;
    float* h    = ws;
    float* T    = ws + 16777216;
    float* xf   = ws + 17039360;
    float* of   = ws + 17104896;
    float* icaT = ws + 17170432;

    k_table<<<32, 256, 0, stream>>>(T);
    k_prep<<<12, 256, 0, stream>>>(ica_w, fc2_w, icaT);
    k_lift<<<dim3(32, 32), 256, 0, stream>>>(x, fc0_w, fc0_b, h);

    for (int l = 0; l < 4; ++l) {
        k_dft<<<512, 256, 0, stream>>>(h, T, xf);
        k_mix<<<128, 256, 0, stream>>>(xf, cwr + (size_t)l * WC * WC * NM,
                                       cwi + (size_t)l * WC * WC * NM, of);
        k_update<<<dim3(32, 32), 256, 0, stream>>>(h, T, of,
                                                   pw_w + (size_t)l * WC * WC,
                                                   pw_b + (size_t)l * WC,
                                                   (l < 3) ? 1 : 0);
    }

    k_final<<<dim3(32, 32), 256, 0, stream>>>(h, fc1_w, fc1_b, icaT, ica_b, out, tc);
}